// Round 6
// baseline (135.740 us; speedup 1.0000x reference)
//
#include <hip/hip_runtime.h>
#include <stdint.h>

// ---------------------------------------------------------------------------
// PlaneEmbeddingNetwork, round 12: zero-LDS, full MFMA C-fragment chaining.
// R11 (45us, VALUBusy 49%, MfmaUtil 10%) proved MFMA absorbs the dot work;
// remaining cost = LDS redistribution machinery (~885 VALU/wave) + serial
// MFMA->LDS->VALU hops. R12 deletes the LDS via index dualities:
//  - C-output (col=lane, rows=regs) == next B-operand when contracting over
//    the producer's M dim; same regs = A-frag of M and B-frag of M^T.
//  - q,k computed TRANSPOSED (A=W^T-frag, B=X-gather-regs) -> C packs
//    directly into scores operands. Scores = K.Q^T (S^T), heads via
//    zero-masked comp-halves of A. Softmax column lands IN-LANE (4 regs)
//    for lanes g2==c0>>2: 24 ops, no cross-lane.
//  - PV = V^T.P^T: P^T B-frag = (valid ? packed softmax : 0) -- block-
//    diagonal via masking. V C-out (R11 orientation) IS the V^T A-frag.
//  - O^T chains to h (A=W1^T = same ws words), relu+quad-pool (2 DPP),
//    pooled chains to fco (A=Wfco^T = same ws words, 4x col replication,
//    store from replica 0). fold_w byte-identical to R11.
// MFMA 28->52 (cheap); VALU ~885->~450/wave; LDS 0.
// Predict: 45 -> ~30-35us, VALUBusy ~38%, MfmaUtil ~15%, LDS=0, conflicts=0,
// absmax ~0.0039 (PV accum improves to f32).
// ---------------------------------------------------------------------------

typedef _Float16 v2h __attribute__((ext_vector_type(2)));
typedef __fp16 h4 __attribute__((ext_vector_type(4)));   // MFMA A/B frag
typedef float f32x4 __attribute__((ext_vector_type(4)));
typedef uint32_t u32x2 __attribute__((ext_vector_type(2)));

#define DPP_ROT2 0x4E  // lane t <- (t+2)&3 within quad
#define DPP_XOR1 0xB1  // lane t <- t^1

template<int CTRL>
static __device__ __forceinline__ float dppf(float x) {
    return __builtin_bit_cast(float,
        __builtin_amdgcn_mov_dpp(__builtin_bit_cast(int, x), CTRL, 0xF, 0xF, true));
}

static __device__ __forceinline__ v2h pkh(float a, float b) {
    v2h r; r.x = (_Float16)a; r.y = (_Float16)b; return r;  // RNE (setup only)
}
static __device__ __forceinline__ v2h pkrtz(float a, float b) {
#if __has_builtin(__builtin_amdgcn_cvt_pkrtz)
    return __builtin_bit_cast(v2h, __builtin_amdgcn_cvt_pkrtz(a, b));
#else
    return pkh(a, b);
#endif
}
static __device__ __forceinline__ uint32_t bcu(v2h h) {
    return __builtin_bit_cast(uint32_t, h);
}
static __device__ __forceinline__ h4 mkh4(uint32_t lo, uint32_t hi) {
    u32x2 t; t.x = lo; t.y = hi; return __builtin_bit_cast(h4, t);
}
static __device__ __forceinline__ h4 ld2h(const uint32_t* p) {
    u32x2 t; t.x = p[0]; t.y = p[1]; return __builtin_bit_cast(h4, t);
}
static __device__ __forceinline__ f32x4 mfma16(h4 a, h4 b, f32x4 c) {
    return __builtin_amdgcn_mfma_f32_16x16x16f16(a, b, c, 0, 0, 0);
}
// pack a C fragment (4 f32 regs) into an A/B fragment (4 halves)
static __device__ __forceinline__ h4 packC(f32x4 c) {
    return mkh4(bcu(pkrtz(c[0], c[1])), bcu(pkrtz(c[2], c[3])));
}
// zero-select a fragment (v_cndmask x2 on the packed dwords)
static __device__ __forceinline__ h4 selh(bool keep, h4 x) {
    u32x2 t = __builtin_bit_cast(u32x2, x);
    u32x2 r; r.x = keep ? t.x : 0u; r.y = keep ? t.y : 0u;
    return __builtin_bit_cast(h4, r);
}

// ---------------------------------------------------------------------------
// fold_w: byte-identical to R11 (A-frag of M^T == B-frag of M).
// ws layout (dwords):
//  [0   .. 384): Eqkv[T][l][d]: B-frag of w_in block T (q,k,v)
//  [384 .. 640): Eh[b][l][d]:   B-frag of W1 col-tile b (== A-frag of W1^T)
//  [640 .. 672): b1[c] f32
//  [672 ..1184): Efco[kt*2+n][l][d]: B-frag of 0.25*fco_w (== A-frag of ^T)
// ---------------------------------------------------------------------------
__global__ void fold_w(const float* __restrict__ w_in,
                       const float* __restrict__ w_out,
                       const float* __restrict__ b_out,
                       const float* __restrict__ fc_w,
                       const float* __restrict__ fc_b,
                       const float* __restrict__ fco_w,
                       uint32_t* __restrict__ wsu) {
    const int tid = threadIdx.x;
    if (blockIdx.x == 0) {
        if (tid < 384) {                   // Eqkv
            const int T = tid >> 7, r = tid & 127, l = r >> 1, d = r & 1;
            const int o = 16 * T + (l & 15), k0 = 4 * (l >> 4) + 2 * d;
            wsu[tid] = bcu(pkh(w_in[k0 * 48 + o], w_in[(k0 + 1) * 48 + o]));
        } else if (tid < 640) {            // Eh
            const int i = tid - 384, b = i >> 7, r = i & 127, l = r >> 1, d = r & 1;
            const int c = 16 * b + (l & 15), k0 = 4 * (l >> 4) + 2 * d;
            float a0 = 0.f, a1 = 0.f;
#pragma unroll
            for (int e = 0; e < 16; ++e) {
                a0 = fmaf(w_out[k0 * 16 + e],       fc_w[e * 32 + c], a0);
                a1 = fmaf(w_out[(k0 + 1) * 16 + e], fc_w[e * 32 + c], a1);
            }
            wsu[tid] = bcu(pkh(a0, a1));
        }
    } else {
        if (tid < 32) {                    // b1 (f32)
            float acc = fc_b[tid];
#pragma unroll
            for (int e = 0; e < 16; ++e)
                acc = fmaf(b_out[e], fc_w[e * 32 + tid], acc);
            reinterpret_cast<float*>(wsu)[640 + tid] = acc;
        } else if (tid < 544) {            // Efco (0.25 pooling folded in)
            const int i = tid - 32;
            const int kt = i >> 8, n = (i >> 7) & 1, r = i & 127, l = r >> 1, d = r & 1;
            const int col = 16 * n + (l & 15), k0 = 16 * kt + 4 * (l >> 4) + 2 * d;
            wsu[672 + i] = bcu(pkh(fco_w[k0 * 32 + col] * 0.25f,
                                   fco_w[(k0 + 1) * 32 + col] * 0.25f));
        }
    }
}

__launch_bounds__(256, 4)
__global__ void face_net(const float* __restrict__ node,
                         const int*   __restrict__ fids,
                         const float* __restrict__ b_in,
                         const uint32_t* __restrict__ wsu,
                         const float* __restrict__ fco_b,
                         float* __restrict__ out, int F) {
    const int l   = threadIdx.x & 63;
    const int wid = threadIdx.x >> 6;
    const int token_base = blockIdx.x * 256 + wid * 64;   // wave = 64 tokens
    const int total = 4 * F;
    if (token_base >= total) return;
    const int c0 = l & 15, g2 = l >> 4;

    // ---- gathers up front: lane holds token 16a+c0, comps 4g2..4g2+3.
    //      These regs serve as X A-frag (v) AND X^T B-frag (q', k').
    h4 X[4];
#pragma unroll
    for (int a = 0; a < 4; ++a) {
        int tok = token_base + 16 * a + c0;
        tok = tok < total ? tok : total - 1;
        const int nid = fids[tok];
        const float4 xv = *reinterpret_cast<const float4*>(
            node + (size_t)nid * 16 + g2 * 4);
        X[a] = mkh4(bcu(pkrtz(xv.x, xv.y)), bcu(pkrtz(xv.z, xv.w)));
    }

    // ---- weight fragments (ws hot in cache)
    const h4 WqT  = ld2h(wsu + 0   + l * 2);   // A-frag of Wq^T
    const h4 WkT  = ld2h(wsu + 128 + l * 2);   // A-frag of Wk^T
    const h4 WvB  = ld2h(wsu + 256 + l * 2);   // B-frag of Wv
    const h4 EhA0 = ld2h(wsu + 384 + l * 2);   // A-frag of W1^T, hid 0..15
    const h4 EhA1 = ld2h(wsu + 512 + l * 2);   // A-frag of W1^T, hid 16..31
    const h4 Ef00 = ld2h(wsu + 672 + 0 * 128 + l * 2);  // kt0, oc 0..15
    const h4 Ef01 = ld2h(wsu + 672 + 1 * 128 + l * 2);  // kt0, oc 16..31
    const h4 Ef10 = ld2h(wsu + 672 + 2 * 128 + l * 2);  // kt1, oc 0..15
    const h4 Ef11 = ld2h(wsu + 672 + 3 * 128 + l * 2);  // kt1, oc 16..31

    // ---- biases (row-indexed by 4g2+r or col-indexed by c0)
    const float4 bq4 = *reinterpret_cast<const float4*>(b_in + 4 * g2);
    const float  bv  = b_in[32 + c0];
    const float* b1f = reinterpret_cast<const float*>(wsu) + 640;
    const float4 b10 = *reinterpret_cast<const float4*>(b1f + 4 * g2);
    const float4 b11 = *reinterpret_cast<const float4*>(b1f + 16 + 4 * g2);
    const float4 fb0 = *reinterpret_cast<const float4*>(fco_b + 4 * g2);
    const float4 fb1 = *reinterpret_cast<const float4*>(fco_b + 16 + 4 * g2);

    const bool scoreH0 = (g2 < 2);          // scores A: comps 0..7 = head0
    const bool pvH0    = (c0 < 8);          // PV A: v-comp rows 0..7 = head0
    const bool valid   = (g2 == (c0 >> 2)); // lane holds its face's S column
    const int fbase = token_base >> 2;
    const float C = 0.51006974841f;         // (1/sqrt(8)) * log2(e)
    const f32x4 zz = {0.f, 0.f, 0.f, 0.f};

#pragma unroll
    for (int a = 0; a < 4; ++a) {
        // ---- qkv (q,k transposed; v plain). k-bias dropped (const over keys).
        f32x4 cq = {bq4.x, bq4.y, bq4.z, bq4.w};
        f32x4 cv = {bv, bv, bv, bv};
        const f32x4 Dq = mfma16(WqT, X[a], cq);   // Q^T[qcomp][token]
        const f32x4 Dk = mfma16(WkT, X[a], zz);   // K^T[kcomp][token]
        const f32x4 Dv = mfma16(X[a], WvB, cv);   // V[token][vcomp]
        const h4 qB = packC(Dq);   // B-frag: Q^T (contract comps)
        const h4 kA = packC(Dk);   // A-frag: K[token][comp]
        const h4 vA = packC(Dv);   // A-frag: V^T[vcomp][token]

        // ---- scores: S^T = K.Q^T per head (head = masked comp-half of A)
        const f32x4 S0 = mfma16(selh(scoreH0,  kA), qB, zz);
        const f32x4 S1 = mfma16(selh(!scoreH0, kA), qB, zz);

        // ---- in-lane softmax over the 4 regs (valid lanes: g2==c0>>2)
        const float e00 = __builtin_amdgcn_exp2f(S0[0] * C);
        const float e01 = __builtin_amdgcn_exp2f(S0[1] * C);
        const float e02 = __builtin_amdgcn_exp2f(S0[2] * C);
        const float e03 = __builtin_amdgcn_exp2f(S0[3] * C);
        const float e10 = __builtin_amdgcn_exp2f(S1[0] * C);
        const float e11 = __builtin_amdgcn_exp2f(S1[1] * C);
        const float e12 = __builtin_amdgcn_exp2f(S1[2] * C);
        const float e13 = __builtin_amdgcn_exp2f(S1[3] * C);
        const float r0 = __builtin_amdgcn_rcpf((e00 + e01) + (e02 + e03));
        const float r1 = __builtin_amdgcn_rcpf((e10 + e11) + (e12 + e13));
        // P^T B-frags; block-diagonal structure via zeroing invalid lanes
        const h4 PB0 = selh(valid, mkh4(bcu(pkrtz(e00 * r0, e01 * r0)),
                                        bcu(pkrtz(e02 * r0, e03 * r0))));
        const h4 PB1 = selh(valid, mkh4(bcu(pkrtz(e10 * r1, e11 * r1)),
                                        bcu(pkrtz(e12 * r1, e13 * r1))));

        // ---- PV: O^T = V^T.P^T, heads via masked v-comp rows, C-chained
        f32x4 Ot = mfma16(selh(pvH0,  vA), PB0, zz);
        Ot       = mfma16(selh(!pvH0, vA), PB1, Ot);
        const h4 hB = packC(Ot);   // B-frag: O^T (contract comps)

        // ---- h: h^T = W1^T.O^T (+b1), relu, quad-pool (quads = faces)
        f32x4 ch0 = {b10.x, b10.y, b10.z, b10.w};
        f32x4 ch1 = {b11.x, b11.y, b11.z, b11.w};
        const f32x4 H0 = mfma16(EhA0, hB, ch0);
        const f32x4 H1 = mfma16(EhA1, hB, ch1);
        float pool[8];
#pragma unroll
        for (int r = 0; r < 4; ++r) {
            float x0 = fmaxf(H0[r], 0.f);
            float s0 = x0 + dppf<DPP_XOR1>(x0); s0 = s0 + dppf<DPP_ROT2>(s0);
            pool[r] = s0;
            float x1 = fmaxf(H1[r], 0.f);
            float s1 = x1 + dppf<DPP_XOR1>(x1); s1 = s1 + dppf<DPP_ROT2>(s1);
            pool[4 + r] = s1;
        }
        const h4 pB0 = mkh4(bcu(pkrtz(pool[0], pool[1])),
                            bcu(pkrtz(pool[2], pool[3])));
        const h4 pB1 = mkh4(bcu(pkrtz(pool[4], pool[5])),
                            bcu(pkrtz(pool[6], pool[7])));

        // ---- fco: out^T = Wfco^T.pooled (+b), 2 K-tiles chained, 2 oc-tiles
        f32x4 cf0 = {fb0.x, fb0.y, fb0.z, fb0.w};
        f32x4 cf1 = {fb1.x, fb1.y, fb1.z, fb1.w};
        const f32x4 O0 = mfma16(Ef10, pB1, mfma16(Ef00, pB0, cf0));
        const f32x4 O1 = mfma16(Ef11, pB1, mfma16(Ef01, pB0, cf1));

        // ---- store from replica 0 of each face (cols are 4x replicated)
        if ((c0 & 3) == 0) {
            const int face = fbase + 4 * a + (c0 >> 2);
            float* ob = out + (size_t)face * 32 + 4 * g2;
            *reinterpret_cast<float4*>(ob)      = make_float4(O0[0], O0[1], O0[2], O0[3]);
            *reinterpret_cast<float4*>(ob + 16) = make_float4(O1[0], O1[1], O1[2], O1[3]);
        }
    }
}

extern "C" void kernel_launch(void* const* d_in, const int* in_sizes, int n_in,
                              void* d_out, int out_size, void* d_ws, size_t ws_size,
                              hipStream_t stream) {
    const float* node  = (const float*)d_in[0];
    const int*   fids  = (const int*)  d_in[1];
    const float* w_in  = (const float*)d_in[2];
    const float* b_in  = (const float*)d_in[3];
    const float* w_out = (const float*)d_in[4];
    const float* b_out = (const float*)d_in[5];
    const float* fc_w  = (const float*)d_in[6];
    const float* fc_b  = (const float*)d_in[7];
    const float* fco_w = (const float*)d_in[8];
    const float* fco_b = (const float*)d_in[9];
    float* out = (float*)d_out;
    uint32_t* wsu = (uint32_t*)d_ws;
    const int F = in_sizes[1] / 4;

    hipLaunchKernelGGL(fold_w, dim3(2), dim3(640), 0, stream,
                       w_in, w_out, b_out, fc_w, fc_b, fco_w, wsu);
    const int threads = F * 4;
    const int blocks = (threads + 255) / 256;
    hipLaunchKernelGGL(face_net, dim3(blocks), dim3(256), 0, stream,
                       node, fids, b_in, wsu, fco_b, out, F);
}